// Round 8
// baseline (109.418 us; speedup 1.0000x reference)
//
#include <hip/hip_runtime.h>
#include <hip/hip_bf16.h>

#define D_DIM 1024
#define C_CLS 64
#define N_SUP 4096
#define M_Q   8192
#define LMAX  320
#define LDA   136
#define KQ    256

typedef __attribute__((ext_vector_type(8))) short short8;
typedef __attribute__((ext_vector_type(4))) float f32x4;

__device__ inline unsigned short f2bf(float x) {
    __hip_bfloat16 h = __float2bfloat16(x);
    return __builtin_bit_cast(unsigned short, h);
}

// ---- K_A: fused norms + class aggregation.  One block per class (64 x 512thr).
// Wave w owns members i == w (mod 8); reads FULL rows so the norm is an
// in-wave shuffle reduce (no barriers); register accumulator (16 f32/lane);
// one barrier + 8-wave LDS combine; bf16 write.  gS read exactly once. ----
__global__ __launch_bounds__(512) void k_W(const float* __restrict__ gS,
                                           const int* __restrict__ tgt,
                                           unsigned short* __restrict__ Wb) {
    const int c = blockIdx.x;
    const int t = threadIdx.x, w = t >> 6, l = t & 63;
    __shared__ int cnt;
    __shared__ int lst[LMAX];
    __shared__ float PS[8][D_DIM];    // 32 KB
    if (t == 0) cnt = 0;
    __syncthreads();

    const int4* T4 = reinterpret_cast<const int4*>(tgt);
    for (int q = t; q < N_SUP / 4; q += 512) {
        const int4 v4 = T4[q];
        const int base = q * 4;
        if (v4.x == c) { const int i = atomicAdd(&cnt, 1); if (i < LMAX) lst[i] = base; }
        if (v4.y == c) { const int i = atomicAdd(&cnt, 1); if (i < LMAX) lst[i] = base + 1; }
        if (v4.z == c) { const int i = atomicAdd(&cnt, 1); if (i < LMAX) lst[i] = base + 2; }
        if (v4.w == c) { const int i = atomicAdd(&cnt, 1); if (i < LMAX) lst[i] = base + 3; }
    }
    __syncthreads();
    const int k = min(cnt, LMAX);

    f32x4 acc[4] = {};
    float4 cur[4], nxt[4];
    int i = w;
    if (i < k) {
        const float4* R = reinterpret_cast<const float4*>(gS + (size_t)lst[i] * D_DIM);
#pragma unroll
        for (int q = 0; q < 4; ++q) cur[q] = R[l + 64 * q];
    }
    for (; i < k; i += 8) {
        const int nx = i + 8;
        if (nx < k) {   // prefetch next row while reducing this one
            const float4* R = reinterpret_cast<const float4*>(gS + (size_t)lst[nx] * D_DIM);
#pragma unroll
            for (int q = 0; q < 4; ++q) nxt[q] = R[l + 64 * q];
        }
        float ss = 0.f;
#pragma unroll
        for (int q = 0; q < 4; ++q)
            ss += cur[q].x * cur[q].x + cur[q].y * cur[q].y +
                  cur[q].z * cur[q].z + cur[q].w * cur[q].w;
#pragma unroll
        for (int off = 32; off > 0; off >>= 1) ss += __shfl_xor(ss, off, 64);
        const float rv = rsqrtf(fmaxf(ss, 1e-24f));
#pragma unroll
        for (int q = 0; q < 4; ++q) {
            acc[q].x = fmaf(cur[q].x, rv, acc[q].x);
            acc[q].y = fmaf(cur[q].y, rv, acc[q].y);
            acc[q].z = fmaf(cur[q].z, rv, acc[q].z);
            acc[q].w = fmaf(cur[q].w, rv, acc[q].w);
        }
#pragma unroll
        for (int q = 0; q < 4; ++q) cur[q] = nxt[q];
    }

    // lane l's q-th float4 covers cols [4l + 256q, +3]
#pragma unroll
    for (int q = 0; q < 4; ++q)
        *reinterpret_cast<f32x4*>(&PS[w][q * 256 + l * 4]) = acc[q];
    __syncthreads();
    for (int col = t; col < D_DIM; col += 512) {
        float s = 0.f;
#pragma unroll
        for (int wv = 0; wv < 8; ++wv) s += PS[wv][col];
        Wb[(size_t)c * D_DIM + col] = f2bf(s);
    }
}

// ---- K_B: out[m,c] = rinvF[m] * sum_k fX[m,k]*W[c,k]  (bf16 MFMA) ----
// 512 blocks x 4 waves; block owns 16 rows; wave w owns k-quarter.
// Wave-private A-buffer reused across both 128-col chunks; fused row-sumsq;
// LDS ~35 KB -> 4 blocks/CU capacity.
__global__ __launch_bounds__(256, 4) void k_out_mfma(const float* __restrict__ fX,
                                                     const unsigned short* __restrict__ Wb,
                                                     float* __restrict__ out) {
    __shared__ unsigned short A[4][16 * LDA];  // 17.0 KB, wave-private
    __shared__ float P[4][16][68];             // 17.4 KB, padded stride
    __shared__ float SSred[4][16];
    __shared__ float rinvR[16];

    const int t = threadIdx.x, w = t >> 6, l = t & 63;
    const int m0 = blockIdx.x * 16;
    const float* Ab = fX + (size_t)m0 * D_DIM + w * KQ;

    float4 ld[8];
#pragma unroll
    for (int j = 0; j < 8; ++j) {
        const int f = l + 64 * j, r = f >> 5, c4 = f & 31;
        ld[j] = reinterpret_cast<const float4*>(Ab + (size_t)r * D_DIM)[c4];
    }

    f32x4 acc[4] = {};
    float ssr[8];
#pragma unroll
    for (int j = 0; j < 8; ++j) ssr[j] = 0.f;

#pragma unroll
    for (int ch = 0; ch < 2; ++ch) {
#pragma unroll
        for (int j = 0; j < 8; ++j) {
            const int f = l + 64 * j, r = f >> 5, c4 = f & 31;
            const float4 v = ld[j];
            ssr[j] += v.x * v.x + v.y * v.y + v.z * v.z + v.w * v.w;
            ushort4 b;
            b.x = f2bf(v.x); b.y = f2bf(v.y); b.z = f2bf(v.z); b.w = f2bf(v.w);
            *reinterpret_cast<ushort4*>(&A[w][r * LDA + c4 * 4]) = b;
        }
        if (ch == 0) {   // next chunk's globals fly under this chunk's MFMAs
#pragma unroll
            for (int j = 0; j < 8; ++j) {
                const int f = l + 64 * j, r = f >> 5, c4 = f & 31;
                ld[j] = reinterpret_cast<const float4*>(Ab + (size_t)r * D_DIM + 128)[c4];
            }
        }
#pragma unroll
        for (int ks = 0; ks < 4; ++ks) {
            const short8 a = *reinterpret_cast<const short8*>(
                &A[w][(l & 15) * LDA + (l >> 4) * 8 + ks * 32]);
#pragma unroll
            for (int ct = 0; ct < 4; ++ct) {
                const short8 b = *reinterpret_cast<const short8*>(
                    Wb + (size_t)(ct * 16 + (l & 15)) * D_DIM + w * KQ + ch * 128 +
                    ks * 32 + (l >> 4) * 8);
                acc[ct] = __builtin_amdgcn_mfma_f32_16x16x32_bf16(a, b, acc[ct], 0, 0, 0);
            }
        }
    }

#pragma unroll
    for (int off = 1; off < 32; off <<= 1)
#pragma unroll
        for (int j = 0; j < 8; ++j) ssr[j] += __shfl_xor(ssr[j], off, 64);
    if ((l & 31) == 0) {
#pragma unroll
        for (int j = 0; j < 8; ++j) SSred[w][(l >> 5) + 2 * j] = ssr[j];
    }

#pragma unroll
    for (int ct = 0; ct < 4; ++ct)
#pragma unroll
        for (int r = 0; r < 4; ++r)
            P[w][(l >> 4) * 4 + r][ct * 16 + (l & 15)] = acc[ct][r];
    __syncthreads();
    if (t < 16)
        rinvR[t] = rsqrtf(fmaxf(
            SSred[0][t] + SSred[1][t] + SSred[2][t] + SSred[3][t], 1e-24f));
    __syncthreads();

    const int row = t >> 4, cb = (t & 15) * 4;
    const float* Pr = &P[0][row][cb];
    const f32x4 p0 = *reinterpret_cast<const f32x4*>(Pr);
    const f32x4 p1 = *reinterpret_cast<const f32x4*>(Pr + 16 * 68);
    const f32x4 p2 = *reinterpret_cast<const f32x4*>(Pr + 32 * 68);
    const f32x4 p3 = *reinterpret_cast<const f32x4*>(Pr + 48 * 68);
    const f32x4 o = (p0 + p1 + p2 + p3) * rinvR[row];
    *reinterpret_cast<f32x4*>(out + (size_t)(m0 + row) * C_CLS + cb) = o;
}

extern "C" void kernel_launch(void* const* d_in, const int* in_sizes, int n_in,
                              void* d_out, int out_size, void* d_ws, size_t ws_size,
                              hipStream_t stream) {
    const float* gS  = (const float*)d_in[0];
    const float* fX  = (const float*)d_in[1];
    const int*   tgt = (const int*)d_in[2];
    float* out = (float*)d_out;
    unsigned short* Wb = (unsigned short*)d_ws;   // 128 KB bf16

    hipLaunchKernelGGL(k_W,        dim3(C_CLS),   dim3(512), 0, stream, gS, tgt, Wb);
    hipLaunchKernelGGL(k_out_mfma, dim3(M_Q / 16), dim3(256), 0, stream, fX, Wb, out);
}

// Round 9
// 101.181 us; speedup vs baseline: 1.0814x; 1.0814x over previous
//
#include <hip/hip_runtime.h>
#include <hip/hip_bf16.h>

#define D_DIM 1024
#define C_CLS 64
#define N_SUP 4096
#define M_Q   8192
#define LMAX  320
#define KQ    256

typedef __attribute__((ext_vector_type(8))) short short8;
typedef __attribute__((ext_vector_type(4))) float f32x4;

__device__ inline unsigned short f2bf(float x) {
    __hip_bfloat16 h = __float2bfloat16(x);
    return __builtin_bit_cast(unsigned short, h);
}

// ---- K1: rinv[n] = 1/||gS[n]||. 1024 blocks x 4 waves, 1 row/wave. ----
__global__ __launch_bounds__(256) void k_norms(const float* __restrict__ gS,
                                               float* __restrict__ rinv) {
    const int t = threadIdx.x, l = t & 63;
    const int n = blockIdx.x * 4 + (t >> 6);
    const float4* R = reinterpret_cast<const float4*>(gS + (size_t)n * D_DIM);
    float ss = 0.f;
#pragma unroll
    for (int q = 0; q < 4; ++q) {
        const float4 v = R[l + 64 * q];
        ss += v.x * v.x + v.y * v.y + v.z * v.z + v.w * v.w;
    }
#pragma unroll
    for (int off = 32; off > 0; off >>= 1) ss += __shfl_xor(ss, off, 64);
    if (l == 0) rinv[n] = rsqrtf(fmaxf(ss, 1e-24f));
}

// ---- K2: Wb[c][d] = sum_{tgt[n]==c} gS[n][d]*rinv[n].  1024 blocks =
// 64 classes x 16 chunks of 64 cols; 4 waves take every 4th member;
// gather 4-deep pipelined. (proven in R7) ----
__global__ __launch_bounds__(256) void k_classW(const float* __restrict__ gS,
                                                const int* __restrict__ tgt,
                                                const float* __restrict__ rinv,
                                                unsigned short* __restrict__ Wb) {
    const int c = blockIdx.x >> 4, d0 = (blockIdx.x & 15) * 64;
    const int t = threadIdx.x, h = t >> 6, col = t & 63;
    __shared__ int cnt; __shared__ int lst[LMAX];
    __shared__ float rvs[LMAX]; __shared__ float PP[4][64];
    if (t == 0) cnt = 0;
    __syncthreads();
    const int4* T4 = reinterpret_cast<const int4*>(tgt);
    for (int q = t; q < N_SUP / 4; q += 256) {
        const int4 v4 = T4[q];
        const int base = q * 4;
        if (v4.x == c) { const int i = atomicAdd(&cnt, 1); if (i < LMAX) lst[i] = base; }
        if (v4.y == c) { const int i = atomicAdd(&cnt, 1); if (i < LMAX) lst[i] = base + 1; }
        if (v4.z == c) { const int i = atomicAdd(&cnt, 1); if (i < LMAX) lst[i] = base + 2; }
        if (v4.w == c) { const int i = atomicAdd(&cnt, 1); if (i < LMAX) lst[i] = base + 3; }
    }
    __syncthreads();
    const int k = min(cnt, LMAX);
    for (int i = t; i < k; i += 256) rvs[i] = rinv[lst[i]];
    __syncthreads();

    float acc = 0.f;
    int i = h;
    for (; i + 12 < k; i += 16) {
        const float v0 = gS[(size_t)lst[i] * D_DIM + d0 + col];
        const float v1 = gS[(size_t)lst[i + 4] * D_DIM + d0 + col];
        const float v2 = gS[(size_t)lst[i + 8] * D_DIM + d0 + col];
        const float v3 = gS[(size_t)lst[i + 12] * D_DIM + d0 + col];
        acc = fmaf(v0, rvs[i], acc);
        acc = fmaf(v1, rvs[i + 4], acc);
        acc = fmaf(v2, rvs[i + 8], acc);
        acc = fmaf(v3, rvs[i + 12], acc);
    }
    for (; i < k; i += 4)
        acc = fmaf(gS[(size_t)lst[i] * D_DIM + d0 + col], rvs[i], acc);

    PP[h][col] = acc;
    __syncthreads();
    if (t < 64)
        Wb[(size_t)c * D_DIM + d0 + t] = f2bf(PP[0][t] + PP[1][t] + PP[2][t] + PP[3][t]);
}

// ---- K3: out[m,c] = rinvF[m] * sum_k fX[m,k]*W[c,k]  (bf16 MFMA) ----
// 512 blocks x 4 waves, wave w owns k-quarter. NO A-staging: fX has zero
// cross-wave reuse, so each lane loads its A-fragment bytes directly from
// global (row l&15, k (l>>4)*8 — identical bytes to the staged layout),
// converts in-register. K-loop has no LDS ops and no barriers. Sumsq via
// 2 shuffles (row-mates = lanes l^16, l^32). LDS = 18 KB combine only.
__global__ __launch_bounds__(256, 3) void k_out_mfma(const float* __restrict__ fX,
                                                     const unsigned short* __restrict__ Wb,
                                                     float* __restrict__ out) {
    __shared__ float P[4][16][68];   // 17.4 KB, padded stride
    __shared__ float SSred[4][16];
    __shared__ float rinvR[16];

    const int t = threadIdx.x, w = t >> 6, l = t & 63;
    const int m0 = blockIdx.x * 16;
    const int row = l & 15, p = l >> 4;
    const float* Ap = fX + (size_t)(m0 + row) * D_DIM + w * KQ + p * 8;
    const unsigned short* Bp = Wb + (size_t)row * D_DIM + w * KQ + p * 8;

    f32x4 acc[4] = {};
    float ss = 0.f;

#pragma unroll
    for (int ks = 0; ks < 8; ++ks) {
        const float4 lo = *reinterpret_cast<const float4*>(Ap + ks * 32);
        const float4 hi = *reinterpret_cast<const float4*>(Ap + ks * 32 + 4);
        ss += lo.x * lo.x + lo.y * lo.y + lo.z * lo.z + lo.w * lo.w +
              hi.x * hi.x + hi.y * hi.y + hi.z * hi.z + hi.w * hi.w;
        short8 a;
        a[0] = (short)f2bf(lo.x); a[1] = (short)f2bf(lo.y);
        a[2] = (short)f2bf(lo.z); a[3] = (short)f2bf(lo.w);
        a[4] = (short)f2bf(hi.x); a[5] = (short)f2bf(hi.y);
        a[6] = (short)f2bf(hi.z); a[7] = (short)f2bf(hi.w);
#pragma unroll
        for (int ct = 0; ct < 4; ++ct) {
            const short8 b = *reinterpret_cast<const short8*>(
                Bp + (size_t)ct * 16 * D_DIM + ks * 32);
            acc[ct] = __builtin_amdgcn_mfma_f32_16x16x32_bf16(a, b, acc[ct], 0, 0, 0);
        }
    }

    // row sumsq: this wave's k-quarter lives in lanes {row, row+16, row+32, row+48}
    ss += __shfl_xor(ss, 16, 64);
    ss += __shfl_xor(ss, 32, 64);
    if (p == 0) SSred[w][row] = ss;

    // stash per-wave MFMA partials (C/D: col = l&15, row = p*4 + r)
#pragma unroll
    for (int ct = 0; ct < 4; ++ct)
#pragma unroll
        for (int r = 0; r < 4; ++r)
            P[w][p * 4 + r][ct * 16 + row] = acc[ct][r];
    __syncthreads();
    if (t < 16)
        rinvR[t] = rsqrtf(fmaxf(
            SSred[0][t] + SSred[1][t] + SSred[2][t] + SSred[3][t], 1e-24f));
    __syncthreads();

    const int orow = t >> 4, cb = (t & 15) * 4;
    const float* Pr = &P[0][orow][cb];
    const f32x4 p0 = *reinterpret_cast<const f32x4*>(Pr);
    const f32x4 p1 = *reinterpret_cast<const f32x4*>(Pr + 16 * 68);
    const f32x4 p2 = *reinterpret_cast<const f32x4*>(Pr + 32 * 68);
    const f32x4 p3 = *reinterpret_cast<const f32x4*>(Pr + 48 * 68);
    const f32x4 o = (p0 + p1 + p2 + p3) * rinvR[orow];
    *reinterpret_cast<f32x4*>(out + (size_t)(m0 + orow) * C_CLS + cb) = o;
}

extern "C" void kernel_launch(void* const* d_in, const int* in_sizes, int n_in,
                              void* d_out, int out_size, void* d_ws, size_t ws_size,
                              hipStream_t stream) {
    const float* gS  = (const float*)d_in[0];
    const float* fX  = (const float*)d_in[1];
    const int*   tgt = (const int*)d_in[2];
    float* out = (float*)d_out;

    float* rinv = (float*)d_ws;                                  // 16 KB
    unsigned short* Wb = (unsigned short*)((char*)d_ws + 16384); // 128 KB bf16

    hipLaunchKernelGGL(k_norms,    dim3(N_SUP / 4),  dim3(256), 0, stream, gS, rinv);
    hipLaunchKernelGGL(k_classW,   dim3(C_CLS * 16), dim3(256), 0, stream, gS, tgt, rinv, Wb);
    hipLaunchKernelGGL(k_out_mfma, dim3(M_Q / 16),   dim3(256), 0, stream, fX, Wb, out);
}